// Round 4
// baseline (3706.778 us; speedup 1.0000x reference)
//
#include <hip/hip_runtime.h>
#include <stdint.h>

#define NS   2048
#define NQ   6144
#define NN   8192      // total nodes
#define IND  512
#define DM   256
#define NWAY 64
#define KNB  10
#define NCT  64        // number of 128-wide column tiles (NN/128)

// ---------- helpers ----------

// load 128 rows x 32 cols of a DM-wide row-major matrix, transposed into dst[k][m], stride 132
__device__ __forceinline__ void load_tileT(float* __restrict__ dst, const float* __restrict__ base,
                                           int r0, int kc, int t)
{
    int a  = t >> 1;            // row within tile 0..127
    int cg = (t & 1) * 16;      // col-group base within the 32-wide chunk
    const float* src = base + (size_t)(r0 + a) * DM + kc + cg;
#pragma unroll
    for (int q = 0; q < 4; ++q) {
        float4 v = *reinterpret_cast<const float4*>(src + q * 4);
        dst[(cg + q*4 + 0) * 132 + a] = v.x;
        dst[(cg + q*4 + 1) * 132 + a] = v.y;
        dst[(cg + q*4 + 2) * 132 + a] = v.z;
        dst[(cg + q*4 + 3) * 132 + a] = v.w;
    }
}

// lexicographic (value, index) insert into sorted-ascending top-10 registers
__device__ __forceinline__ void topk_insert(float v, int j, float bval[KNB], int bidx[KNB])
{
    bool better = (v < bval[KNB-1]) || (v == bval[KNB-1] && j < bidx[KNB-1]);
    if (better) {
        float cv = v; int ci = j;
#pragma unroll
        for (int q = 0; q < KNB; ++q) {
            bool sw = (cv < bval[q]) || (cv == bval[q] && ci < bidx[q]);
            if (sw) {
                float tv = bval[q]; bval[q] = cv; cv = tv;
                int   ti = bidx[q]; bidx[q] = ci; ci = ti;
            }
        }
    }
}

// ---------- 1) embed: E = concat(support,query) @ W  (8192x512x256), 64x128 tiles ----------
__global__ __launch_bounds__(256) void embed_kernel(
    const float* __restrict__ support, const float* __restrict__ query,
    const float* __restrict__ W, float* __restrict__ E)
{
    __shared__ float smemA[32 * 68];     // A^T: [k][m], 64 rows
    __shared__ float smemB[32 * 132];    // B:   [k][n], 128 cols
    const int t  = threadIdx.x;
    const int i0 = blockIdx.x * 64;
    const int n0 = blockIdx.y * 128;
    const int tx = t & 15, ty = t >> 4;

    float acc[4][8];
#pragma unroll
    for (int m = 0; m < 4; ++m)
#pragma unroll
        for (int n = 0; n < 8; ++n) acc[m][n] = 0.f;

    for (int kc = 0; kc < IND; kc += 32) {
        // A: rows i0..i0+64 of concat(support,query), cols kc..kc+32, transposed
        {
            int a  = t >> 2;            // 0..63
            int cg = (t & 3) * 8;       // 0,8,16,24
            int g  = i0 + a;
            const float* src = (g < NS) ? (support + (size_t)g * IND)
                                        : (query + (size_t)(g - NS) * IND);
            src += kc + cg;
#pragma unroll
            for (int q = 0; q < 2; ++q) {
                float4 v = *reinterpret_cast<const float4*>(src + q * 4);
                smemA[(cg + q*4 + 0) * 68 + a] = v.x;
                smemA[(cg + q*4 + 1) * 68 + a] = v.y;
                smemA[(cg + q*4 + 2) * 68 + a] = v.z;
                smemA[(cg + q*4 + 3) * 68 + a] = v.w;
            }
        }
        // B: W rows kc..kc+32, cols n0..n0+128 (k-major already)
        {
            int r  = t >> 3;            // 0..31
            int cg = (t & 7) * 16;      // 0..112
            const float* src = W + (size_t)(kc + r) * DM + n0 + cg;
#pragma unroll
            for (int q = 0; q < 4; ++q) {
                float4 v = *reinterpret_cast<const float4*>(src + q * 4);
                *reinterpret_cast<float4*>(&smemB[r * 132 + cg + q * 4]) = v;
            }
        }
        __syncthreads();
#pragma unroll
        for (int kk = 0; kk < 32; ++kk) {
            float4 a0 = *reinterpret_cast<const float4*>(&smemA[kk * 68 + ty * 4]);
            float4 b0 = *reinterpret_cast<const float4*>(&smemB[kk * 132 + tx * 8]);
            float4 b1 = *reinterpret_cast<const float4*>(&smemB[kk * 132 + tx * 8 + 4]);
            float af[4] = {a0.x, a0.y, a0.z, a0.w};
            float bf[8] = {b0.x, b0.y, b0.z, b0.w, b1.x, b1.y, b1.z, b1.w};
#pragma unroll
            for (int m = 0; m < 4; ++m)
#pragma unroll
                for (int n = 0; n < 8; ++n)
                    acc[m][n] += af[m] * bf[n];
        }
        __syncthreads();
    }
#pragma unroll
    for (int m = 0; m < 4; ++m) {
        int row = i0 + ty * 4 + m;
        float4 v0 = make_float4(acc[m][0], acc[m][1], acc[m][2], acc[m][3]);
        float4 v1 = make_float4(acc[m][4], acc[m][5], acc[m][6], acc[m][7]);
        *reinterpret_cast<float4*>(&E[(size_t)row * DM + n0 + tx * 8])     = v0;
        *reinterpret_cast<float4*>(&E[(size_t)row * DM + n0 + tx * 8 + 4]) = v1;
    }
}

// ---------- 2) row squared norms ----------
__global__ __launch_bounds__(256) void sq_kernel(const float* __restrict__ E, float* __restrict__ sq)
{
    int t = threadIdx.x;
    int w = t >> 6, l = t & 63;
    int row = blockIdx.x * 4 + w;
    const float* e = E + (size_t)row * DM;
    float s = 0.f;
#pragma unroll
    for (int q = 0; q < 4; ++q) { float x = e[l + q * 64]; s += x * x; }
#pragma unroll
    for (int off = 32; off >= 1; off >>= 1) s += __shfl_xor(s, off, 64);
    if (l == 0) sq[row] = s;
}

// ---------- 3) fused distance GEMM + streaming per-row top-10 ----------
// grid (64 row-blocks, nsplit column-splits); split s covers column tiles
// [s*NCT/nsplit, (s+1)*NCT/nsplit) — uneven counts are fine (lexicographic merge).
// NO min-waves launch-bounds arg: on this toolchain the cap is ~256/arg, so
// arg=4 -> 64 VGPR and arg=3 -> 84 VGPR, both spilling acc[8][8] (~1 GB/dispatch
// scratch traffic, r2/r3). Natural allocation is 144 VGPR = 3 waves/SIMD =
// 3 blocks/CU with zero spills; grid 64x12=768 = exactly 3/CU.
__global__ __launch_bounds__(256) void dist_topk_kernel(
    const float* __restrict__ E, const float* __restrict__ sq,
    float* __restrict__ cval, int* __restrict__ cidx,
    int nsplit, int cstride)
{
    // 33792 B total. GEMM phase: A=[0,32*132), B=[32*132,64*132).
    // Epilogue: same buffer re-used as 64x128 half-tile D2 staging (32768 B).
    __shared__ float smem[2 * 32 * 132];
    float* smemA = smem;
    float* smemB = smem + 32 * 132;
    const int t     = threadIdx.x;
    const int i0    = blockIdx.x * 128;
    const int split = blockIdx.y;
    const int tx = t & 15, ty = t >> 4;

    const int jtb = (split * NCT) / nsplit;
    const int jte = ((split + 1) * NCT) / nsplit;

    float bval[KNB]; int bidx[KNB];
#pragma unroll
    for (int s = 0; s < KNB; ++s) { bval[s] = 3.0e38f; bidx[s] = 0x7fffffff; }

    for (int jt = jtb; jt < jte; ++jt) {
        const int j0 = jt * 128;
        float acc[8][8];
#pragma unroll
        for (int m = 0; m < 8; ++m)
#pragma unroll
            for (int n = 0; n < 8; ++n) acc[m][n] = 0.f;

        for (int kc = 0; kc < DM; kc += 32) {
            load_tileT(smemA, E, i0, kc, t);
            load_tileT(smemB, E, j0, kc, t);
            __syncthreads();
#pragma unroll
            for (int kk = 0; kk < 32; ++kk) {
                float4 a0 = *reinterpret_cast<const float4*>(&smemA[kk * 132 + ty * 8]);
                float4 a1 = *reinterpret_cast<const float4*>(&smemA[kk * 132 + ty * 8 + 4]);
                float4 b0 = *reinterpret_cast<const float4*>(&smemB[kk * 132 + tx * 8]);
                float4 b1 = *reinterpret_cast<const float4*>(&smemB[kk * 132 + tx * 8 + 4]);
                float af[8] = {a0.x, a0.y, a0.z, a0.w, a1.x, a1.y, a1.z, a1.w};
                float bf[8] = {b0.x, b0.y, b0.z, b0.w, b1.x, b1.y, b1.z, b1.w};
#pragma unroll
                for (int m = 0; m < 8; ++m)
#pragma unroll
                    for (int n = 0; n < 8; ++n)
                        acc[m][n] += af[m] * bf[n];
            }
            __syncthreads();
        }
        // epilogue: d2 = sq_i + sq_j - 2*dot, clamped; two-phase 64x128 staging.
        // Store permutation: element (r, c) with c = tx*8+n lands at physical col
        //   q = tx*8 + ((n + (tx>>2) + 4*((r>>3)&3)) & 7)
        // -> each scalar-store instruction hits 32 banks at 2-way (free).
        float sqc[8];
#pragma unroll
        for (int n = 0; n < 8; ++n) sqc[n] = sq[j0 + tx * 8 + n];

        // ---- phase 0: rows 0..63 (threads with ty < 8 store) ----
        if (ty < 8) {
#pragma unroll
            for (int m = 0; m < 8; ++m) {
                int r = ty * 8 + m;
                float sr = sq[i0 + r];
                int swz = (ty & 3) * 4;
#pragma unroll
                for (int n = 0; n < 8; ++n) {
                    float d2 = sr + sqc[n] - 2.0f * acc[m][n];
                    int p = (n + (tx >> 2) + swz) & 7;
                    smem[r * 128 + tx * 8 + p] = fmaxf(d2, 0.0f);
                }
            }
        }
        __syncthreads();
        if (t < 64) {
            const float* rowp = &smem[t * 128];
            int swz = (t >> 3) & 3;
            for (int s = 0; s < 128; ++s) {
                int pp = (s + t) & 127;
                float v = rowp[pp];
                int g = pp >> 3, pe = pp & 7;
                int c = g * 8 + ((pe - (g >> 2) - 4 * swz) & 7);
                topk_insert(v, j0 + c, bval, bidx);
            }
        }
        __syncthreads();
        // ---- phase 1: rows 64..127 (threads with ty >= 8 store) ----
        if (ty >= 8) {
#pragma unroll
            for (int m = 0; m < 8; ++m) {
                int r = ty * 8 + m;           // 64..127
                float sr = sq[i0 + r];
                int swz = (ty & 3) * 4;
#pragma unroll
                for (int n = 0; n < 8; ++n) {
                    float d2 = sr + sqc[n] - 2.0f * acc[m][n];
                    int p = (n + (tx >> 2) + swz) & 7;
                    smem[(r - 64) * 128 + tx * 8 + p] = fmaxf(d2, 0.0f);
                }
            }
        }
        __syncthreads();
        if (t >= 64 && t < 128) {
            const float* rowp = &smem[(t - 64) * 128];
            int swz = (t >> 3) & 3;
            for (int s = 0; s < 128; ++s) {
                int pp = (s + t) & 127;
                float v = rowp[pp];
                int g = pp >> 3, pe = pp & 7;
                int c = g * 8 + ((pe - (g >> 2) - 4 * swz) & 7);
                topk_insert(v, j0 + c, bval, bidx);
            }
        }
        __syncthreads();
    }
    if (t < 128) {
        int row = i0 + t;
        size_t base = (size_t)row * cstride + split * KNB;
#pragma unroll
        for (int s = 0; s < KNB; ++s) {
            cval[base + s] = bval[s];
            cidx[base + s] = bidx[s];
        }
    }
}

// ---------- 4) merge partial top-10s -> global top-10, build symmetric adjacency bitset ----------
__global__ __launch_bounds__(256) void merge_adj_kernel(
    const float* __restrict__ cval, const int* __restrict__ cidx,
    unsigned int* __restrict__ bits, int ncand, int cstride)
{
    int i = blockIdx.x * blockDim.x + threadIdx.x;
    if (i >= NN) return;
    float bval[KNB]; int bidx[KNB];
#pragma unroll
    for (int s = 0; s < KNB; ++s) { bval[s] = 3.0e38f; bidx[s] = 0x7fffffff; }
    for (int s = 0; s < ncand; ++s) {
        float v = cval[(size_t)i * cstride + s];
        int   j = cidx[(size_t)i * cstride + s];
        topk_insert(v, j, bval, bidx);
    }
#pragma unroll
    for (int s = 0; s < KNB; ++s) {
        int j = bidx[s];
        atomicOr(&bits[(size_t)i * 256 + (j >> 5)], 1u << (j & 31));
        atomicOr(&bits[(size_t)j * 256 + (i >> 5)], 1u << (i & 31));
    }
}

// ---------- 5) label init ----------
__global__ __launch_bounds__(256) void labels_init_kernel(const int* __restrict__ slab, float* __restrict__ la)
{
    int tid = blockIdx.x * blockDim.x + threadIdx.x;   // NN*64 threads
    int i = tid >> 6, c = tid & 63;
    float v = 0.f;
    if (i < NS) v = (slab[i] == c) ? 1.f : 0.f;
    la[tid] = v;
}

// ---------- 6) one propagation step: lout[i] = (1/deg_i) * sum_{j in N(i)} lin[j] ----------
__global__ __launch_bounds__(256) void prop_kernel(
    const unsigned int* __restrict__ bits, const float* __restrict__ lin, float* __restrict__ lout)
{
    int i = blockIdx.x * 4 + (threadIdx.x >> 6);
    int c = threadIdx.x & 63;
    const unsigned int* row = bits + (size_t)i * 256;
    int deg = 0;
    for (int w = 0; w < 256; ++w) deg += __popc(row[w]);
    float tinv = 1.0f / (float)deg;                    // deg >= 1 (self-loop always present)
    float acc = 0.f;
    for (int w = 0; w < 256; ++w) {
        unsigned int m = row[w];
        while (m) {
            int b = __ffs(m) - 1;
            m &= m - 1;
            int j = w * 32 + b;
            acc += __fmul_rn(tinv, lin[(size_t)j * 64 + c]);
        }
    }
    lout[(size_t)i * 64 + c] = acc;
}

// ---------- 7) argmax (first-index tie-break) -> one-hot ----------
__global__ __launch_bounds__(256) void argmax_kernel(const float* __restrict__ labels, float* __restrict__ out)
{
    int q = blockIdx.x * 4 + (threadIdx.x >> 6);   // 0..NQ-1
    int c = threadIdx.x & 63;
    float bv = labels[(size_t)(NS + q) * 64 + c];
    int   bi = c;
#pragma unroll
    for (int off = 32; off >= 1; off >>= 1) {
        float ov = __shfl_xor(bv, off, 64);
        int   oi = __shfl_xor(bi, off, 64);
        if (ov > bv || (ov == bv && oi < bi)) { bv = ov; bi = oi; }
    }
    out[(size_t)q * 64 + c] = (c == bi) ? 1.0f : 0.0f;
}

// ---------- launch ----------
extern "C" void kernel_launch(void* const* d_in, const int* in_sizes, int n_in,
                              void* d_out, int out_size, void* d_ws, size_t ws_size,
                              hipStream_t stream)
{
    const float* support = (const float*)d_in[0];
    const float* query   = (const float*)d_in[1];
    const int*   slab    = (const int*)d_in[2];
    const float* W       = (const float*)d_in[3];
    float* out = (float*)d_out;
    char*  ws  = (char*)d_ws;

    // workspace layout (phase-aliased):
    //   [0, 8M)     E (fp32 8192x256)  -> later reused as adjacency bitset (8192x256 u32)
    //   [8M, +32K)  sq
    //   then cval / cidx (size depends on nsplit)  -> later reused as labels_a / labels_b
    const size_t candOff = 8388608 + 32768;            // 8,421,376
    // 12 splits -> grid 64x12 = 768 blocks = exactly 3/CU (one full residency wave,
    // no ragged tail). Fallback to 8 if workspace is tight.
    int nsplit = 8;
    if (ws_size >= candOff + 2ull * (size_t)NN * 12 * KNB * 4 + 16) nsplit = 12;
    const int cstride = nsplit * KNB;
    const size_t candBytes = (size_t)NN * cstride * 4;

    float*        E    = (float*)(ws + 0);
    unsigned int* bits = (unsigned int*)(ws + 0);
    float*        sq   = (float*)(ws + 8388608);
    float*        cval = (float*)(ws + candOff);
    int*          cidx = (int*)  (ws + candOff + candBytes);
    float*        la   = (float*)(ws + candOff);               // aliases cval (dead after merge)
    float*        lb   = (float*)(ws + candOff + candBytes);   // aliases cidx (dead after merge)

    embed_kernel<<<dim3(128, 2), 256, 0, stream>>>(support, query, W, E);
    sq_kernel<<<2048, 256, 0, stream>>>(E, sq);
    dist_topk_kernel<<<dim3(64, nsplit), 256, 0, stream>>>(E, sq, cval, cidx, nsplit, cstride);
    hipMemsetAsync(bits, 0, (size_t)NN * 256 * sizeof(unsigned int), stream);   // E dead now
    merge_adj_kernel<<<NN / 256, 256, 0, stream>>>(cval, cidx, bits, cstride, cstride);
    labels_init_kernel<<<(NN * 64) / 256, 256, 0, stream>>>(slab, la);          // cval dead now
    prop_kernel<<<NN / 4, 256, 0, stream>>>(bits, la, lb);
    prop_kernel<<<NN / 4, 256, 0, stream>>>(bits, lb, la);
    prop_kernel<<<NN / 4, 256, 0, stream>>>(bits, la, lb);
    argmax_kernel<<<NQ / 4, 256, 0, stream>>>(lb, out);
}

// Round 5
// 1111.873 us; speedup vs baseline: 3.3338x; 3.3338x over previous
//
#include <hip/hip_runtime.h>
#include <stdint.h>

#define NS   2048
#define NQ   6144
#define NN   8192      // total nodes
#define IND  512
#define DM   256
#define KNB  10
#define NSPLIT 8

typedef short bf16x8 __attribute__((ext_vector_type(8)));
typedef float f32x4  __attribute__((ext_vector_type(4)));

// exact RNE fp32 -> bf16 (bits), no denormal concerns (bf16 exp range == fp32)
__device__ __forceinline__ unsigned short f2bf(float v)
{
    unsigned int u = __float_as_uint(v);
    unsigned int r = (u + 0x7fffu + ((u >> 16) & 1u)) >> 16;
    return (unsigned short)r;
}
__device__ __forceinline__ float bf2f(unsigned short h)
{
    return __uint_as_float(((unsigned int)h) << 16);
}

// lexicographic (value, index) insert into sorted-ascending top-10 registers
__device__ __forceinline__ void topk_insert(float v, int j, float bval[KNB], int bidx[KNB])
{
    bool better = (v < bval[KNB-1]) || (v == bval[KNB-1] && j < bidx[KNB-1]);
    if (better) {
        float cv = v; int ci = j;
#pragma unroll
        for (int q = 0; q < KNB; ++q) {
            bool sw = (cv < bval[q]) || (cv == bval[q] && ci < bidx[q]);
            if (sw) {
                float tv = bval[q]; bval[q] = cv; cv = tv;
                int   ti = bidx[q]; bidx[q] = ci; ci = ti;
            }
        }
    }
}

// ---------- 1) embed: E = concat(support,query) @ W (8192x512x256), 64x128 tiles.
// Epilogue packs E into MFMA-fragment-ordered bf16 hi/lo arrays
//   G[c][node][q][j]  (c=k/32, q=(k>>3)&3, j=k&7; 16 B per (node,q))
// and writes per-row partial squared norms (exact fp32 from acc).
__global__ __launch_bounds__(256) void embed_kernel(
    const float* __restrict__ support, const float* __restrict__ query,
    const float* __restrict__ W, bf16x8* __restrict__ Ghi, bf16x8* __restrict__ Glo,
    float* __restrict__ sqpart)
{
    __shared__ float smemA[32 * 68];     // A^T: [k][m], 64 rows
    __shared__ float smemB[32 * 132];    // B:   [k][n], 128 cols
    __shared__ float sqred[64 * 17];
    const int t  = threadIdx.x;
    const int i0 = blockIdx.x * 64;
    const int n0 = blockIdx.y * 128;
    const int tx = t & 15, ty = t >> 4;

    float acc[4][8];
#pragma unroll
    for (int m = 0; m < 4; ++m)
#pragma unroll
        for (int n = 0; n < 8; ++n) acc[m][n] = 0.f;

    for (int kc = 0; kc < IND; kc += 32) {
        {
            int a  = t >> 2;            // 0..63
            int cg = (t & 3) * 8;       // 0,8,16,24
            int g  = i0 + a;
            const float* src = (g < NS) ? (support + (size_t)g * IND)
                                        : (query + (size_t)(g - NS) * IND);
            src += kc + cg;
#pragma unroll
            for (int q = 0; q < 2; ++q) {
                float4 v = *reinterpret_cast<const float4*>(src + q * 4);
                smemA[(cg + q*4 + 0) * 68 + a] = v.x;
                smemA[(cg + q*4 + 1) * 68 + a] = v.y;
                smemA[(cg + q*4 + 2) * 68 + a] = v.z;
                smemA[(cg + q*4 + 3) * 68 + a] = v.w;
            }
        }
        {
            int r  = t >> 3;            // 0..31
            int cg = (t & 7) * 16;      // 0..112
            const float* src = W + (size_t)(kc + r) * DM + n0 + cg;
#pragma unroll
            for (int q = 0; q < 4; ++q) {
                float4 v = *reinterpret_cast<const float4*>(src + q * 4);
                *reinterpret_cast<float4*>(&smemB[r * 132 + cg + q * 4]) = v;
            }
        }
        __syncthreads();
#pragma unroll
        for (int kk = 0; kk < 32; ++kk) {
            float4 a0 = *reinterpret_cast<const float4*>(&smemA[kk * 68 + ty * 4]);
            float4 b0 = *reinterpret_cast<const float4*>(&smemB[kk * 132 + tx * 8]);
            float4 b1 = *reinterpret_cast<const float4*>(&smemB[kk * 132 + tx * 8 + 4]);
            float af[4] = {a0.x, a0.y, a0.z, a0.w};
            float bf[8] = {b0.x, b0.y, b0.z, b0.w, b1.x, b1.y, b1.z, b1.w};
#pragma unroll
            for (int m = 0; m < 4; ++m)
#pragma unroll
                for (int n = 0; n < 8; ++n)
                    acc[m][n] += af[m] * bf[n];
        }
        __syncthreads();
    }
    // epilogue: pack hi/lo bf16 fragments + partial row norms
    const int cc = blockIdx.y * 4 + (tx >> 2);   // k-chunk
    const int qq = tx & 3;                       // quad within chunk
#pragma unroll
    for (int m = 0; m < 4; ++m) {
        int row = i0 + ty * 4 + m;
        bf16x8 h8, l8;
        float s = 0.f;
#pragma unroll
        for (int n = 0; n < 8; ++n) {
            float v = acc[m][n];
            unsigned short hu = f2bf(v);
            float hf = bf2f(hu);
            unsigned short lu = f2bf(v - hf);
            h8[n] = (short)hu;
            l8[n] = (short)lu;
            s += v * v;
        }
        size_t gi = ((size_t)cc * NN + row) * 4 + qq;
        Ghi[gi] = h8;
        Glo[gi] = l8;
        sqred[(ty * 4 + m) * 17 + tx] = s;
    }
    __syncthreads();
    if (t < 64) {
        float s = 0.f;
#pragma unroll
        for (int x = 0; x < 16; ++x) s += sqred[t * 17 + x];
        sqpart[(size_t)blockIdx.y * NN + i0 + t] = s;
    }
}

// ---------- 2) combine the two column-half partial norms ----------
__global__ __launch_bounds__(256) void sqsum_kernel(const float* __restrict__ sqpart,
                                                    float* __restrict__ sq)
{
    int i = blockIdx.x * 256 + threadIdx.x;
    sq[i] = sqpart[i] + sqpart[NN + i];
}

// ---------- 3) fused distance MFMA-GEMM + streaming per-row top-10 ----------
// bf16 2-way split (hi+lo), 4 MFMA products into one fp32 acc: d2 error ~2e-5,
// at the fp32 summation-order noise level (proven tolerable in r1).
// Block 128x128, 4 waves in 2x2, wave tile 64x64 = 4x4 MFMA 16x16x32 tiles.
// Fragments loaded straight from packed global arrays (L2-resident, 1KB/instr
// perfectly coalesced) — no LDS in GEMM phase. LDS = double-buffered 64x132 D2
// staging; waves 0,1 store rows 0..63 in buf0 while waves 2,3 store 64..127 in
// buf1; then each wave pair scans the OTHER buffer (all 256 threads active,
// 2 barriers per column tile).
__global__ __launch_bounds__(256) void dist_topk_kernel(
    const bf16x8* __restrict__ Ghi, const bf16x8* __restrict__ Glo,
    const float* __restrict__ sq, float* __restrict__ cval, int* __restrict__ cidx)
{
    __shared__ float smem[2][64 * 132];          // 67584 B
    const int t  = threadIdx.x;
    const int l  = t & 63, w = t >> 6;
    const int wr = w >> 1, wc = w & 1;
    const int lm = l & 15, q = l >> 4;
    const int i0 = blockIdx.x * 128;
    const int split = blockIdx.y;

    // hoisted row norms: acc reg r of m-tile mt maps to row 16*mt + 4*q + r
    f32x4 sqr[4];
#pragma unroll
    for (int mt = 0; mt < 4; ++mt)
        sqr[mt] = *reinterpret_cast<const f32x4*>(&sq[i0 + 64 * wr + 16 * mt + 4 * q]);

    const size_t aBase = (size_t)(i0 + 64 * wr + lm) * 4 + q;   // f16x8 units
    const int    cb    = 64 * wc + lm;

    float bval[KNB]; int bidx[KNB];
#pragma unroll
    for (int s = 0; s < KNB; ++s) { bval[s] = 3.0e38f; bidx[s] = 0x7fffffff; }

    for (int jt = split * 8; jt < split * 8 + 8; ++jt) {
        const int j0 = jt * 128;
        const size_t bBase = (size_t)(j0 + cb) * 4 + q;

        f32x4 acc[4][4];
#pragma unroll
        for (int mt = 0; mt < 4; ++mt)
#pragma unroll
            for (int nt = 0; nt < 4; ++nt) acc[mt][nt] = (f32x4){0.f, 0.f, 0.f, 0.f};

        for (int c = 0; c < 8; ++c) {
            const size_t co = (size_t)c * (NN * 4);
            bf16x8 Ah[4], Al[4], Bh[4], Bl[4];
#pragma unroll
            for (int mt = 0; mt < 4; ++mt) {
                Ah[mt] = Ghi[aBase + co + mt * 64];
                Al[mt] = Glo[aBase + co + mt * 64];
            }
#pragma unroll
            for (int nt = 0; nt < 4; ++nt) {
                Bh[nt] = Ghi[bBase + co + nt * 64];
                Bl[nt] = Glo[bBase + co + nt * 64];
            }
#pragma unroll
            for (int mt = 0; mt < 4; ++mt)
#pragma unroll
                for (int nt = 0; nt < 4; ++nt) {
                    f32x4 a = acc[mt][nt];
                    a = __builtin_amdgcn_mfma_f32_16x16x32_bf16(Ah[mt], Bh[nt], a, 0, 0, 0);
                    a = __builtin_amdgcn_mfma_f32_16x16x32_bf16(Ah[mt], Bl[nt], a, 0, 0, 0);
                    a = __builtin_amdgcn_mfma_f32_16x16x32_bf16(Al[mt], Bh[nt], a, 0, 0, 0);
                    a = __builtin_amdgcn_mfma_f32_16x16x32_bf16(Al[mt], Bl[nt], a, 0, 0, 0);
                    acc[mt][nt] = a;
                }
        }
        // epilogue: d2 into LDS (store pattern is 2-way-bank = free)
        float* buf = smem[wr];
#pragma unroll
        for (int nt = 0; nt < 4; ++nt) {
            float sqc = sq[j0 + 64 * wc + 16 * nt + lm];
#pragma unroll
            for (int mt = 0; mt < 4; ++mt)
#pragma unroll
                for (int r = 0; r < 4; ++r) {
                    float d2 = sqr[mt][r] + sqc - 2.0f * acc[mt][nt][r];
                    buf[(16 * mt + 4 * q + r) * 132 + 64 * wc + 16 * nt + lm] = fmaxf(d2, 0.0f);
                }
        }
        __syncthreads();
        {
            // threads 0..127 scan buf1 (rows 64..127), threads 128..255 scan buf0
            const float* sbuf = (t < 128) ? smem[1] : smem[0];
            const int tt = t & 127;
            const int r  = tt >> 1;            // local row 0..63
            const int h  = (tt & 1) << 6;      // column half
            const float* rowp = &sbuf[r * 132 + h];
            for (int s = 0; s < 64; ++s) {
                int cc2 = (s + r) & 63;        // rotation kills serialization
                topk_insert(rowp[cc2], j0 + h + cc2, bval, bidx);
            }
        }
        __syncthreads();
    }
    // merge the two column-half lists per row via LDS, then write 10/row/split
    float* exv = smem[0];
    int*   exi = reinterpret_cast<int*>(&smem[0][1280]);
    if (t & 1) {
#pragma unroll
        for (int s = 0; s < KNB; ++s) {
            exv[(t >> 1) * KNB + s] = bval[s];
            exi[(t >> 1) * KNB + s] = bidx[s];
        }
    }
    __syncthreads();
    if (!(t & 1)) {
#pragma unroll
        for (int s = 0; s < KNB; ++s)
            topk_insert(exv[(t >> 1) * KNB + s], exi[(t >> 1) * KNB + s], bval, bidx);
        int row = i0 + ((t < 128) ? 64 : 0) + ((t & 127) >> 1);
        size_t base = (size_t)row * (NSPLIT * KNB) + split * KNB;
#pragma unroll
        for (int s = 0; s < KNB; ++s) {
            cval[base + s] = bval[s];
            cidx[base + s] = bidx[s];
        }
    }
}

// ---------- 4) merge partial top-10s -> global top-10, build symmetric adjacency bitset ----------
__global__ __launch_bounds__(256) void merge_adj_kernel(
    const float* __restrict__ cval, const int* __restrict__ cidx,
    unsigned int* __restrict__ bits)
{
    int i = blockIdx.x * blockDim.x + threadIdx.x;
    if (i >= NN) return;
    float bval[KNB]; int bidx[KNB];
#pragma unroll
    for (int s = 0; s < KNB; ++s) { bval[s] = 3.0e38f; bidx[s] = 0x7fffffff; }
    for (int s = 0; s < NSPLIT * KNB; ++s) {
        float v = cval[(size_t)i * (NSPLIT * KNB) + s];
        int   j = cidx[(size_t)i * (NSPLIT * KNB) + s];
        topk_insert(v, j, bval, bidx);
    }
#pragma unroll
    for (int s = 0; s < KNB; ++s) {
        int j = bidx[s];
        atomicOr(&bits[(size_t)i * 256 + (j >> 5)], 1u << (j & 31));
        atomicOr(&bits[(size_t)j * 256 + (i >> 5)], 1u << (i & 31));
    }
}

// ---------- 5) label init ----------
__global__ __launch_bounds__(256) void labels_init_kernel(const int* __restrict__ slab, float* __restrict__ la)
{
    int tid = blockIdx.x * blockDim.x + threadIdx.x;   // NN*64 threads
    int i = tid >> 6, c = tid & 63;
    float v = 0.f;
    if (i < NS) v = (slab[i] == c) ? 1.f : 0.f;
    la[tid] = v;
}

// ---------- 6) one propagation step: lout[i] = (1/deg_i) * sum_{j in N(i)} lin[j] ----------
__global__ __launch_bounds__(256) void prop_kernel(
    const unsigned int* __restrict__ bits, const float* __restrict__ lin, float* __restrict__ lout)
{
    int i = blockIdx.x * 4 + (threadIdx.x >> 6);
    int c = threadIdx.x & 63;
    const unsigned int* row = bits + (size_t)i * 256;
    int deg = 0;
    for (int w = 0; w < 256; ++w) deg += __popc(row[w]);
    float tinv = 1.0f / (float)deg;                    // deg >= 1 (self-loop always present)
    float acc = 0.f;
    for (int w = 0; w < 256; ++w) {
        unsigned int m = row[w];
        while (m) {
            int b = __ffs(m) - 1;
            m &= m - 1;
            int j = w * 32 + b;
            acc += __fmul_rn(tinv, lin[(size_t)j * 64 + c]);
        }
    }
    lout[(size_t)i * 64 + c] = acc;
}

// ---------- 7) argmax (first-index tie-break) -> one-hot ----------
__global__ __launch_bounds__(256) void argmax_kernel(const float* __restrict__ labels, float* __restrict__ out)
{
    int q = blockIdx.x * 4 + (threadIdx.x >> 6);   // 0..NQ-1
    int c = threadIdx.x & 63;
    float bv = labels[(size_t)(NS + q) * 64 + c];
    int   bi = c;
#pragma unroll
    for (int off = 32; off >= 1; off >>= 1) {
        float ov = __shfl_xor(bv, off, 64);
        int   oi = __shfl_xor(bi, off, 64);
        if (ov > bv || (ov == bv && oi < bi)) { bv = ov; bi = oi; }
    }
    out[(size_t)q * 64 + c] = (c == bi) ? 1.0f : 0.0f;
}

// ---------- launch ----------
extern "C" void kernel_launch(void* const* d_in, const int* in_sizes, int n_in,
                              void* d_out, int out_size, void* d_ws, size_t ws_size,
                              hipStream_t stream)
{
    const float* support = (const float*)d_in[0];
    const float* query   = (const float*)d_in[1];
    const int*   slab    = (const int*)d_in[2];
    const float* W       = (const float*)d_in[3];
    float* out = (float*)d_out;
    char*  ws  = (char*)d_ws;

    // workspace (phase-aliased), total 13,729,792 B:
    //   [0,        4.00M)  Ghi (bf16 hi, fragment-packed)   -> bits [0,8M) after dist
    //   [4.00M,    8.00M)  Glo (bf16 lo)
    //   [8.00M,   +64K  )  sqpart (2 x 8192)
    //   [8.0625M, +32K  )  sq
    //   [8.094M,  +2.5M )  cval -> la after merge
    //   [10.59M,  +2.5M )  cidx -> lb after merge
    const size_t GHI_OFF = 0;
    const size_t GLO_OFF = 4194304;
    const size_t SQP_OFF = 8388608;
    const size_t SQ_OFF  = 8454144;
    const size_t CV_OFF  = 8486912;
    const size_t CI_OFF  = 11108352;

    bf16x8*       Ghi  = (bf16x8*)(ws + GHI_OFF);
    bf16x8*       Glo  = (bf16x8*)(ws + GLO_OFF);
    unsigned int* bits = (unsigned int*)(ws + GHI_OFF);       // aliases Ghi+Glo (dead after dist)
    float*        sqp  = (float*)(ws + SQP_OFF);
    float*        sq   = (float*)(ws + SQ_OFF);
    float*        cval = (float*)(ws + CV_OFF);
    int*          cidx = (int*)  (ws + CI_OFF);
    float*        la   = (float*)(ws + CV_OFF);               // aliases cval (dead after merge)
    float*        lb   = (float*)(ws + CI_OFF);               // aliases cidx

    embed_kernel<<<dim3(128, 2), 256, 0, stream>>>(support, query, W, Ghi, Glo, sqp);
    sqsum_kernel<<<NN / 256, 256, 0, stream>>>(sqp, sq);
    dist_topk_kernel<<<dim3(64, NSPLIT), 256, 0, stream>>>(Ghi, Glo, sq, cval, cidx);
    hipMemsetAsync(bits, 0, (size_t)NN * 256 * sizeof(unsigned int), stream);   // Ghi/Glo dead now
    merge_adj_kernel<<<NN / 256, 256, 0, stream>>>(cval, cidx, bits);
    labels_init_kernel<<<(NN * 64) / 256, 256, 0, stream>>>(slab, la);          // cval dead now
    prop_kernel<<<NN / 4, 256, 0, stream>>>(bits, la, lb);
    prop_kernel<<<NN / 4, 256, 0, stream>>>(bits, lb, la);
    prop_kernel<<<NN / 4, 256, 0, stream>>>(bits, la, lb);
    argmax_kernel<<<NQ / 4, 256, 0, stream>>>(lb, out);
}